// Round 1
// baseline (91.997 us; speedup 1.0000x reference)
//
#include <hip/hip_runtime.h>
#include <hip/hip_bf16.h>

// PairRE scoring: out[b,n] = -|| t_hat[n]*rt[b] - h_hat[b]*rh[b] ||_2
// B=512, N=2048, E=256.
//
// x(b,n) = dot([T^2 | T]_n , [rt^2 | -2*rt*Hh]_b) + c_b,
//   T = t/||t||, Hh = (h/||h||)*rh, c_b = ||Hh_b||^2.
//
// R5 (fusion round): counters showed the two previous dispatches together
// account for <10 us of roofline work (1.07 GFLOP MFMA ~0.5us, ~50 MB L2
// ~1.5us, ~10 MB HBM ~1.5us) vs 68 us measured -> the cost is dispatch
// count / serialization, not bandwidth or compute. So: ONE kernel. Each
// block preps its own 32(b) x 32(n) tile's bf16 fragments into 64 KB of
// LDS (wave-per-row, numerics identical to R4 -> same absmax), one
// barrier, then the same packed-fragment MFMA chain, now fed from LDS.
// Workspace unused. Redundant prep reads (~133 MB L2 total) cost ~4 us of
// L2 BW spread across 1024 blocks, overlapped (2 blocks/CU resident).
//
// LDS layout = R4's packed-fragment layout, 16B units:
//   unit(g,s,q,m) = g*1024 + s*64 + q*16 + m   (T groups g=0,1; A at +2048)
// Write pattern (row m fixed, lane -> s_=lane>>2, q=lane&3) puts all 64
// lanes at start-bank 4m%32 (4-bank pileup, ~8x write slowdown). XOR
// swizzle on the 16B-unit index, applied on BOTH write and read:
//   SWZ16(a) = a ^ ((a>>4)&7)
// -> writes: bank index low3 = m^(q|(s_&1)<<2), 8 lanes per bank-quad,
//    8 words/bank (optimal). reads (s fixed, lane varies): low3 =
//    (l%8)^((l>>4)|(s&1)<<2), also exactly 8 words/bank. Conflict-free
//    both directions.
//
// XCD locality: gridDim.x=64 is divisible by 8, so linear block id % 8 ==
// blockIdx.x % 8 -> all 16 blocks sharing one tail slice (same bx, all by)
// land on the same XCD; tail slice + head + rel (~3 MB) stay L2-resident.

#define B_DIM 512
#define N_DIM 2048
#define E_DIM 256
#define K_DIM 512
#define NSTEP 16        // K/32 MFMA k-steps

typedef __attribute__((ext_vector_type(8))) __bf16 bf16x8;
typedef __attribute__((ext_vector_type(4))) float f32x4;

__device__ inline ushort f2bf(float x) {
    __hip_bfloat16 h = __float2bfloat16(x);   // RNE
    union { __hip_bfloat16 b; ushort u; } cv_; cv_.b = h; return cv_.u;
}

__device__ inline float wave_sum(float v) {
#pragma unroll
    for (int m = 1; m < 64; m <<= 1) v += __shfl_xor(v, m, 64);
    return v;
}

// 16B-unit index swizzle: XORs (q | (s_&1)<<2) resp. ((l>>4) | (s&1)<<2)
// into the low-3 (row) bits -> 8 words/bank on both ds_write and ds_read.
#define SWZ16(a) ((a) ^ (((a) >> 4) & 7))

__global__ __launch_bounds__(256) void fused_kernel(
        const float* __restrict__ head, const float* __restrict__ tail,
        const float* __restrict__ rel,  const int* __restrict__ rid,
        float* __restrict__ out) {
    // 64 KB fragments: units [0,2048) = T (2 groups of 16 n-rows),
    //                  units [2048,4096) = A (2 groups of 16 b-rows).
    __shared__ ushort frag[4096 * 8];
    __shared__ float cv[32];          // c_b for the block's 32 b-rows

    const int tid = threadIdx.x, lane = tid & 63, wv = tid >> 6;
    const int bx = blockIdx.x, by = blockIdx.y;
    const int s_ = lane >> 2, q = lane & 3;   // k-step / 8-elem sub within step
    const int k0 = lane * 8;
    const bool sqr = (k0 < E_DIM);            // first K-half: squared terms
    const int e0 = k0 & (E_DIM - 1);

    // ---------------- phase 1: prep 64 rows (32 T + 32 A), wave-per-row ----
    for (int i = 0; i < 16; ++i) {
        const int r = wv + 4 * i;             // wave-uniform row id 0..63
        if (r < 32) {
            // T row: n = bx*32 + r. Fragment value at k: k<256 -> t_hat^2,
            // else t_hat. (identical math to R4 prep)
            const int ln = r;
            const int n = bx * 32 + ln;
            const float* row = tail + (size_t)n * E_DIM;
            const float4 v4 = ((const float4*)row)[lane];
            const float ssum = wave_sum(v4.x * v4.x + v4.y * v4.y +
                                        v4.z * v4.z + v4.w * v4.w);
            const float inv = 1.0f / fmaxf(sqrtf(ssum), 1e-12f);
            const float4 f0 = *(const float4*)(row + e0);
            const float4 f1 = *(const float4*)(row + e0 + 4);
            const float v[8] = {f0.x, f0.y, f0.z, f0.w, f1.x, f1.y, f1.z, f1.w};
            ushort u[8];
#pragma unroll
            for (int j = 0; j < 8; ++j) {
                float x = v[j] * inv;
                if (sqr) x *= x;
                u[j] = f2bf(x);
            }
            const int g = ln >> 4, m = ln & 15;
            const int a16 = g * 1024 + s_ * 64 + q * 16 + m;
            *(uint4*)(frag + (size_t)SWZ16(a16) * 8) = *(const uint4*)u;
        } else {
            // A row: b = by*32 + (r-32). Fragment: k<256 -> rt^2, else
            // -2*rt*Hh. Also c_b = ||Hh||^2 into LDS.
            const int lb = r - 32;
            const int b = by * 32 + lb;
            const int id = rid[b];
            const float* hrow  = head + (size_t)b * E_DIM;
            const float* rhrow = rel + (size_t)id * (2 * E_DIM);
            const float* rtrow = rhrow + E_DIM;
            const float4 h4  = ((const float4*)hrow)[lane];
            const float4 rh4 = ((const float4*)rhrow)[lane];
            const float s1 = wave_sum(h4.x * h4.x + h4.y * h4.y +
                                      h4.z * h4.z + h4.w * h4.w);
            const float inv = 1.0f / fmaxf(sqrtf(s1), 1e-12f);
            const float p0 = h4.x * inv * rh4.x, p1 = h4.y * inv * rh4.y;
            const float p2 = h4.z * inv * rh4.z, p3 = h4.w * inv * rh4.w;
            const float s2 = wave_sum(p0 * p0 + p1 * p1 + p2 * p2 + p3 * p3);
            if (lane == 0) cv[lb] = s2;

            const float4 rt0 = *(const float4*)(rtrow + e0);
            const float4 rt1 = *(const float4*)(rtrow + e0 + 4);
            const float rt[8] = {rt0.x, rt0.y, rt0.z, rt0.w,
                                 rt1.x, rt1.y, rt1.z, rt1.w};
            float v[8];
            if (sqr) {
#pragma unroll
                for (int j = 0; j < 8; ++j) v[j] = rt[j] * rt[j];
            } else {
                const float4 h0 = *(const float4*)(hrow + e0);
                const float4 h1 = *(const float4*)(hrow + e0 + 4);
                const float4 r0 = *(const float4*)(rhrow + e0);
                const float4 r1 = *(const float4*)(rhrow + e0 + 4);
                const float hh[8] = {h0.x, h0.y, h0.z, h0.w,
                                     h1.x, h1.y, h1.z, h1.w};
                const float rr[8] = {r0.x, r0.y, r0.z, r0.w,
                                     r1.x, r1.y, r1.z, r1.w};
#pragma unroll
                for (int j = 0; j < 8; ++j)
                    v[j] = -2.0f * rt[j] * (hh[j] * inv * rr[j]);
            }
            ushort u[8];
#pragma unroll
            for (int j = 0; j < 8; ++j) u[j] = f2bf(v[j]);
            const int g = lb >> 4, m = lb & 15;
            const int a16 = 2048 + g * 1024 + s_ * 64 + q * 16 + m;
            *(uint4*)(frag + (size_t)SWZ16(a16) * 8) = *(const uint4*)u;
        }
    }

    __syncthreads();

    // ---------------- phase 2: MFMA from LDS, one (A,T) group pair / wave --
    const int gAl = wv & 1;          // which 16 b-rows
    const int gTl = wv >> 1;         // which 16 n-cols
    const int baseA = 2048 + gAl * 1024;
    const int baseT = gTl * 1024;

    f32x4 acc = {0.f, 0.f, 0.f, 0.f};
#pragma unroll
    for (int s = 0; s < NSTEP; ++s) {
        const int aA = baseA + s * 64 + lane;
        const int aT = baseT + s * 64 + lane;
        const bf16x8 fa = *(const bf16x8*)(frag + (size_t)SWZ16(aA) * 8);
        const bf16x8 ft = *(const bf16x8*)(frag + (size_t)SWZ16(aT) * 8);
        acc = __builtin_amdgcn_mfma_f32_16x16x32_bf16(fa, ft, acc, 0, 0, 0);
    }

    // Epilogue: C layout col=lane&15 (n), row=(lane>>4)*4+r (b). Same as R4.
    const int ml = lane & 15, qq = lane >> 4;
    const int n = bx * 32 + gTl * 16 + ml;
#pragma unroll
    for (int r = 0; r < 4; ++r) {
        const int bl = gAl * 16 + qq * 4 + r;
        const float x = acc[r] + cv[bl];
        out[(size_t)(by * 32 + bl) * N_DIM + n] = -sqrtf(fmaxf(x, 0.f));
    }
}

extern "C" void kernel_launch(void* const* d_in, const int* in_sizes, int n_in,
                              void* d_out, int out_size, void* d_ws, size_t ws_size,
                              hipStream_t stream) {
    const float* head = (const float*)d_in[0];
    const float* tail = (const float*)d_in[1];
    const float* rel  = (const float*)d_in[2];
    const int*   rid  = (const int*)d_in[3];
    float* out = (float*)d_out;
    (void)d_ws; (void)ws_size;   // workspace unused: single fused dispatch

    dim3 grid(N_DIM / 32, B_DIM / 32);   // (64, 16) = 1024 blocks, 256 thr
    fused_kernel<<<grid, 256, 0, stream>>>(head, tail, rel, rid, out);
}